// Round 5
// baseline (703.397 us; speedup 1.0000x reference)
//
#include <hip/hip_runtime.h>
#include <hip/hip_bf16.h>
#include <math.h>

#define N_NODES  50000
#define N_EDGES  800000
#define FDIM     128
#define N_GRAPHS 500
#define NEG_SLOPE 0.2f
#define EN_TOTAL (N_EDGES + N_NODES)
#define NPW 8
#define SCAN_NB ((N_NODES + 255) / 256)   // 196

static __device__ __forceinline__ float lrelu(float x) {
    return x >= 0.f ? x : NEG_SLOPE * x;
}

// ---------------- h = X @ W ; asrc = h . a_src ; adst = h . a_dst ----------------
// R3 structure: no LDS. Wave = one column-half (64 cols, 1 col/lane); W column
// values streamed from L1/L2 (64KB, resident). X rows are wave-uniform scalar
// loads. NPW=8 nodes per wave-iteration: 1 W-load + 8 FMA per k. H stored bf16.
__global__ __launch_bounds__(256) void gemm_attn(
    const float* __restrict__ X, const float* __restrict__ W,
    const float* __restrict__ Avs, const float* __restrict__ Avd,
    __hip_bfloat16* __restrict__ Hb, float* __restrict__ asrcN, float* __restrict__ adstN)
{
    const int w = threadIdx.x >> 6, lane = threadIdx.x & 63;
    const int colHalf = w & 1, strm = w >> 1;
    const int c = colHalf * 64 + lane;
    const float as_c = Avs[c];
    const float ad_c = Avd[c];

    const int streamStride = gridDim.x * 2 * NPW;
    for (int base0 = (blockIdx.x * 2 + strm) * NPW; base0 < N_NODES; base0 += streamStride) {
        const int b = __builtin_amdgcn_readfirstlane(base0);
        const float* xr[NPW];
        #pragma unroll
        for (int n = 0; n < NPW; ++n)
            xr[n] = X + (size_t)min(b + n, N_NODES - 1) * FDIM;

        float acc[NPW];
        #pragma unroll
        for (int n = 0; n < NPW; ++n) acc[n] = 0.f;

        #pragma unroll
        for (int k = 0; k < FDIM; ++k) {
            const float wk = W[k * FDIM + c];
            #pragma unroll
            for (int n = 0; n < NPW; ++n)
                acc[n] = fmaf(xr[n][k], wk, acc[n]);
        }

        #pragma unroll
        for (int n = 0; n < NPW; ++n) {
            const int node = b + n;
            const bool ok = (node < N_NODES);
            if (ok) Hb[(size_t)node * FDIM + c] = __float2bfloat16(acc[n]);
            float ps = acc[n] * as_c;
            float pd = acc[n] * ad_c;
            #pragma unroll
            for (int o = 1; o <= 32; o <<= 1) {
                ps += __shfl_xor(ps, o);
                pd += __shfl_xor(pd, o);
            }
            if (ok && lane == 0) {
                atomicAdd(&asrcN[node], ps);
                atomicAdd(&adstN[node], pd);
            }
        }
    }
}

// ---------------- CSR build ----------------
__global__ void count_edges(const int* __restrict__ ei, int* __restrict__ cnt) {
    int i = blockIdx.x * 256 + threadIdx.x;
    if (i < EN_TOTAL) {
        int d = (i < N_EDGES) ? ei[N_EDGES + i] : (i - N_EDGES);
        atomicAdd(&cnt[d], 1);
    }
}

__global__ __launch_bounds__(256) void scan_block(const int* __restrict__ cnt,
                                                  int* __restrict__ off,
                                                  int* __restrict__ blockSums) {
    __shared__ int s[256];
    const int i = blockIdx.x * 256 + threadIdx.x;
    s[threadIdx.x] = (i < N_NODES) ? cnt[i] : 0;
    __syncthreads();
    #pragma unroll
    for (int d = 1; d < 256; d <<= 1) {
        int t = (threadIdx.x >= d) ? s[threadIdx.x - d] : 0;
        __syncthreads();
        s[threadIdx.x] += t;
        __syncthreads();
    }
    if (i < N_NODES) off[i + 1] = s[threadIdx.x];
    if (threadIdx.x == 255) blockSums[blockIdx.x] = s[255];
}

__global__ __launch_bounds__(256) void scan_sums(int* __restrict__ blockSums) {
    __shared__ int s[256];
    s[threadIdx.x] = (threadIdx.x < SCAN_NB) ? blockSums[threadIdx.x] : 0;
    __syncthreads();
    #pragma unroll
    for (int d = 1; d < 256; d <<= 1) {
        int t = (threadIdx.x >= d) ? s[threadIdx.x - d] : 0;
        __syncthreads();
        s[threadIdx.x] += t;
        __syncthreads();
    }
    if (threadIdx.x < SCAN_NB)
        blockSums[threadIdx.x] = (threadIdx.x == 0) ? 0 : s[threadIdx.x - 1];
}

__global__ __launch_bounds__(256) void add_base(int* __restrict__ off,
                                                const int* __restrict__ blockSums) {
    const int i = blockIdx.x * 256 + threadIdx.x;
    if (i < N_NODES) off[i + 1] += blockSums[blockIdx.x];
    if (i == 0) off[0] = 0;
}

__global__ void scatter_edges(const int* __restrict__ ei, const int* __restrict__ off,
                              int* __restrict__ cur, int* __restrict__ srcs) {
    int i = blockIdx.x * 256 + threadIdx.x;
    if (i < EN_TOTAL) {
        int s, d;
        if (i < N_EDGES) { s = ei[i]; d = ei[N_EDGES + i]; }
        else             { s = d = i - N_EDGES; }
        int p = off[d] + atomicAdd(&cur[d], 1);
        srcs[p] = s;
    }
}

// ---------------- segment softmax + weighted aggregation (bf16 H gather) ----------------
// One wave per dst node; 8 edge-groups x 8 feature-lanes (16 feats = 32B = 2 x uint4).
__global__ __launch_bounds__(256) void gat_aggregate(
    const __hip_bfloat16* __restrict__ Hb, const int* __restrict__ off,
    const int* __restrict__ srcs,
    const float* __restrict__ asrcN, const float* __restrict__ adstN,
    const float* __restrict__ bias, float* __restrict__ OUT, int doRelu)
{
    const int wave = threadIdx.x >> 6, lane = threadIdx.x & 63;
    const int grp = lane >> 3, fl = lane & 7;

    for (int n = blockIdx.x * 4 + wave; n < N_NODES; n += gridDim.x * 4) {
        const int s0 = off[n], s1 = off[n + 1];
        const int deg = s1 - s0;
        const float ad = adstN[n];

        // pass 1: per-edge logits, lane-parallel; keep first 64 in registers
        float e_reg = -1e30f;
        float m = -1e30f;
        for (int j = s0 + lane; j < s1; j += 64) {
            float e = lrelu(asrcN[srcs[j]] + ad);
            if (j - s0 < 64) e_reg = e;
            m = fmaxf(m, e);
        }
        #pragma unroll
        for (int o = 32; o; o >>= 1) m = fmaxf(m, __shfl_xor(m, o));

        // pass 2: 8 edges in flight; lane owns 16 bf16 features (32B)
        float4 a0 = {0,0,0,0}, a1 = {0,0,0,0}, a2 = {0,0,0,0}, a3 = {0,0,0,0};
        float dn = 0.f;
        const __hip_bfloat16* Hf = Hb + (size_t)fl * 16;
        for (int j = s0 + grp; j < s1; j += 8) {
            const int s = srcs[j];
            const float ex = (deg <= 64)
                ? __expf(__shfl(e_reg, j - s0) - m)
                : __expf(lrelu(asrcN[s] + ad) - m);
            dn += ex;
            const uint4* hp = (const uint4*)(Hf + (size_t)s * FDIM);
            const uint4 u0 = hp[0], u1 = hp[1];
            a0.x += ex * __uint_as_float(u0.x << 16);
            a0.y += ex * __uint_as_float(u0.x & 0xffff0000u);
            a0.z += ex * __uint_as_float(u0.y << 16);
            a0.w += ex * __uint_as_float(u0.y & 0xffff0000u);
            a1.x += ex * __uint_as_float(u0.z << 16);
            a1.y += ex * __uint_as_float(u0.z & 0xffff0000u);
            a1.z += ex * __uint_as_float(u0.w << 16);
            a1.w += ex * __uint_as_float(u0.w & 0xffff0000u);
            a2.x += ex * __uint_as_float(u1.x << 16);
            a2.y += ex * __uint_as_float(u1.x & 0xffff0000u);
            a2.z += ex * __uint_as_float(u1.y << 16);
            a2.w += ex * __uint_as_float(u1.y & 0xffff0000u);
            a3.x += ex * __uint_as_float(u1.z << 16);
            a3.y += ex * __uint_as_float(u1.z & 0xffff0000u);
            a3.z += ex * __uint_as_float(u1.w << 16);
            a3.w += ex * __uint_as_float(u1.w & 0xffff0000u);
        }

        #pragma unroll
        for (int o = 8; o <= 32; o <<= 1) {
            dn  += __shfl_xor(dn, o);
            a0.x += __shfl_xor(a0.x, o); a0.y += __shfl_xor(a0.y, o);
            a0.z += __shfl_xor(a0.z, o); a0.w += __shfl_xor(a0.w, o);
            a1.x += __shfl_xor(a1.x, o); a1.y += __shfl_xor(a1.y, o);
            a1.z += __shfl_xor(a1.z, o); a1.w += __shfl_xor(a1.w, o);
            a2.x += __shfl_xor(a2.x, o); a2.y += __shfl_xor(a2.y, o);
            a2.z += __shfl_xor(a2.z, o); a2.w += __shfl_xor(a2.w, o);
            a3.x += __shfl_xor(a3.x, o); a3.y += __shfl_xor(a3.y, o);
            a3.z += __shfl_xor(a3.z, o); a3.w += __shfl_xor(a3.w, o);
        }

        if (grp == 0) {
            const float rd = 1.f / dn;
            const float4* bp = (const float4*)(bias + fl * 16);
            float4 ov[4] = {a0, a1, a2, a3};
            float4* op = (float4*)(OUT + (size_t)n * FDIM + fl * 16);
            #pragma unroll
            for (int q = 0; q < 4; ++q) {
                float4 b4 = bp[q];
                float4 o4;
                o4.x = ov[q].x * rd + b4.x; o4.y = ov[q].y * rd + b4.y;
                o4.z = ov[q].z * rd + b4.z; o4.w = ov[q].w * rd + b4.w;
                if (doRelu) {
                    o4.x = fmaxf(o4.x, 0.f); o4.y = fmaxf(o4.y, 0.f);
                    o4.z = fmaxf(o4.z, 0.f); o4.w = fmaxf(o4.w, 0.f);
                }
                op[q] = o4;
            }
        }
    }
}

// ---------------- global mean pool (batch sorted) + final linear ----------------
__global__ __launch_bounds__(128) void pool_linear(
    const float* __restrict__ H, const int* __restrict__ batch,
    const float* __restrict__ Wlin, const float* __restrict__ blin,
    float* __restrict__ out)
{
    const int g = blockIdx.x, f = threadIdx.x;
    int a = 0, b = N_NODES;
    while (a < b) { int mid = (a + b) >> 1; if (batch[mid] < g) a = mid + 1; else b = mid; }
    const int lo = a;
    b = N_NODES;
    while (a < b) { int mid = (a + b) >> 1; if (batch[mid] <= g) a = mid + 1; else b = mid; }
    const int hi = a;

    float acc = 0.f;
    for (int n = lo; n < hi; ++n) acc += H[(size_t)n * FDIM + f];
    const float pooled = acc / fmaxf((float)(hi - lo), 1.0f);

    __shared__ float red0[128], red1[128];
    red0[f] = pooled * Wlin[f * 2 + 0];
    red1[f] = pooled * Wlin[f * 2 + 1];
    __syncthreads();
    for (int st = 64; st; st >>= 1) {
        if (f < st) { red0[f] += red0[f + st]; red1[f] += red1[f + st]; }
        __syncthreads();
    }
    if (f == 0) {
        out[g * 2 + 0] = red0[0] + blin[0];
        out[g * 2 + 1] = red1[0] + blin[1];
    }
}

extern "C" void kernel_launch(void* const* d_in, const int* in_sizes, int n_in,
                              void* d_out, int out_size, void* d_ws, size_t ws_size,
                              hipStream_t stream)
{
    const float* x     = (const float*)d_in[0];
    const int*   ei    = (const int*)d_in[1];
    const int*   batch = (const int*)d_in[2];
    const float* W[3]    = {(const float*)d_in[3],  (const float*)d_in[7],  (const float*)d_in[11]};
    const float* avs[3]  = {(const float*)d_in[4],  (const float*)d_in[8],  (const float*)d_in[12]};
    const float* avd[3]  = {(const float*)d_in[5],  (const float*)d_in[9],  (const float*)d_in[13]};
    const float* bias[3] = {(const float*)d_in[6],  (const float*)d_in[10], (const float*)d_in[14]};
    const float* Wlin = (const float*)d_in[15];
    const float* blin = (const float*)d_in[16];
    float* out = (float*)d_out;

    char* w = (char*)d_ws;
    __hip_bfloat16* Hb = (__hip_bfloat16*)w; w += (size_t)N_NODES * FDIM * 2;  // 12.8 MB
    float* hO    = (float*)w; w += (size_t)N_NODES * FDIM * 4;                 // 25.6 MB
    float* attn  = (float*)w; w += 2 * 200192;
    int*   off   = (int*)w;   w += 200192;
    int*   cnt   = (int*)w;   w += 200192;
    int*   bsum  = (int*)w;   w += 4096;
    int*   srcs  = (int*)w;   w += (size_t)EN_TOTAL * 4;
    float* asrcN = attn;
    float* adstN = attn + N_NODES;

    // ---- CSR by destination (topology shared across layers) ----
    hipMemsetAsync(cnt, 0, N_NODES * sizeof(int), stream);
    count_edges<<<(EN_TOTAL + 255) / 256, 256, 0, stream>>>(ei, cnt);
    scan_block<<<SCAN_NB, 256, 0, stream>>>(cnt, off, bsum);
    scan_sums<<<1, 256, 0, stream>>>(bsum);
    add_base<<<SCAN_NB, 256, 0, stream>>>(off, bsum);
    hipMemsetAsync(cnt, 0, N_NODES * sizeof(int), stream);
    scatter_edges<<<(EN_TOTAL + 255) / 256, 256, 0, stream>>>(ei, off, cnt, srcs);

    // ---- 3 GAT layers ----
    const float* hin = x;
    for (int l = 0; l < 3; ++l) {
        hipMemsetAsync(attn, 0, 2 * N_NODES * sizeof(float), stream);
        gemm_attn<<<768, 256, 0, stream>>>(hin, W[l], avs[l], avd[l], Hb, asrcN, adstN);
        gat_aggregate<<<2048, 256, 0, stream>>>(Hb, off, srcs, asrcN, adstN, bias[l], hO,
                                                (l < 2) ? 1 : 0);
        hin = hO;
    }

    // ---- mean pool + linear ----
    pool_linear<<<N_GRAPHS, 128, 0, stream>>>(hO, batch, Wlin, blin, out);
}

// Round 6
// 392.992 us; speedup vs baseline: 1.7899x; 1.7899x over previous
//
#include <hip/hip_runtime.h>
#include <math.h>

#define N_NODES  50000
#define N_EDGES  800000
#define FDIM     128
#define N_GRAPHS 500
#define NEG_SLOPE 0.2f
#define EN_TOTAL (N_EDGES + N_NODES)
#define SCAN_NB ((N_NODES + 255) / 256)   // 196

typedef short bf16x8 __attribute__((ext_vector_type(8)));
typedef float f32x4 __attribute__((ext_vector_type(4)));

static __device__ __forceinline__ float lrelu(float x) {
    return x >= 0.f ? x : NEG_SLOPE * x;
}
static __device__ __forceinline__ unsigned short f2bf(float v) {
    unsigned int u = __float_as_uint(v);
    u += 0x7fffu + ((u >> 16) & 1u);
    return (unsigned short)(u >> 16);
}
static __device__ __forceinline__ float bf2f(unsigned short s) {
    return __uint_as_float(((unsigned int)s) << 16);
}

// ---------------- split X fp32 -> bf16 hi/lo planes ----------------
__global__ __launch_bounds__(256) void prep_planes(
    const float* __restrict__ X, unsigned short* __restrict__ hi,
    unsigned short* __restrict__ lo)
{
    const int total = N_NODES * FDIM / 4;
    for (int i = blockIdx.x * 256 + threadIdx.x; i < total; i += gridDim.x * 256) {
        const float4 v = ((const float4*)X)[i];
        ushort4 h4, l4;
        h4.x = f2bf(v.x); l4.x = f2bf(v.x - bf2f(h4.x));
        h4.y = f2bf(v.y); l4.y = f2bf(v.y - bf2f(h4.y));
        h4.z = f2bf(v.z); l4.z = f2bf(v.z - bf2f(h4.z));
        h4.w = f2bf(v.w); l4.w = f2bf(v.w - bf2f(h4.w));
        ((ushort4*)hi)[i] = h4;
        ((ushort4*)lo)[i] = l4;
    }
}

// ---------------- h = X @ W via split-bf16 MFMA (3 passes, fp32-accurate) ------
// Block = 256 thr = 4 waves; wave w computes rows m0..m0+15 x all 128 cols.
// W staged in LDS transposed [c][kk] bf16 hi/lo, one 64-k half at a time,
// 16B-block XOR swizzle (T2) so the 16-lane column-slice ds_read_b128 is
// conflict-free. A-frags read directly from global hi/lo planes (vector path).
// Epilogue: Hb bf16 store + in-wave asrc/adst dots (no atomics).
__global__ __launch_bounds__(256) void gemm_mfma(
    const unsigned short* __restrict__ Ahi, const unsigned short* __restrict__ Alo,
    const float* __restrict__ W,
    const float* __restrict__ Avs, const float* __restrict__ Avd,
    unsigned short* __restrict__ Hb, float* __restrict__ asrcN, float* __restrict__ adstN)
{
    __shared__ unsigned short sH[128 * 64];   // 16 KB  [c][kk], swizzled
    __shared__ unsigned short sL[128 * 64];   // 16 KB

    const int tid = threadIdx.x, wv = tid >> 6, lane = tid & 63;
    const int r16 = lane & 15, g = lane >> 4;
    const int m0 = blockIdx.x * 64 + wv * 16;
    const bool valid = (m0 < N_NODES);

    float as_r[8], ad_r[8];
    if (valid) {
        #pragma unroll
        for (int t = 0; t < 8; ++t) {
            as_r[t] = Avs[t * 16 + r16];
            ad_r[t] = Avd[t * 16 + r16];
        }
    }

    f32x4 acc[8];
    #pragma unroll
    for (int t = 0; t < 8; ++t) acc[t] = (f32x4){0.f, 0.f, 0.f, 0.f};

    const size_t rowA = valid ? (size_t)(m0 + r16) * FDIM : 0;

    for (int half = 0; half < 2; ++half) {
        const int kb = half * 64;
        if (half) __syncthreads();           // readers of previous half done
        // stage W rows kb..kb+63, transposed + split, swizzled
        for (int q = tid; q < 2048; q += 256) {
            const int kk = q >> 5;                 // 0..63
            const int c0 = (q & 31) * 4;
            const float4 v = *(const float4*)(W + (size_t)(kb + kk) * FDIM + c0);
            const float vv[4] = {v.x, v.y, v.z, v.w};
            #pragma unroll
            for (int j = 0; j < 4; ++j) {
                const int c = c0 + j;
                const int off = (c * 128 + kk * 2) ^ ((c & 7) << 4);
                const unsigned short h = f2bf(vv[j]);
                const unsigned short l = f2bf(vv[j] - bf2f(h));
                *(unsigned short*)((char*)sH + off) = h;
                *(unsigned short*)((char*)sL + off) = l;
            }
        }
        __syncthreads();

        if (valid) {
            #pragma unroll
            for (int cc = 0; cc < 2; ++cc) {
                const int k0 = kb + cc * 32;           // global k base of chunk
                const int kkf = cc * 32 + 8 * g;       // within-half k of my slot
                const bf16x8 ah = *(const bf16x8*)(Ahi + rowA + k0 + 8 * g);
                const bf16x8 al = *(const bf16x8*)(Alo + rowA + k0 + 8 * g);
                #pragma unroll
                for (int t = 0; t < 8; ++t) {
                    const int c = t * 16 + r16;
                    const int off = (c * 128 + kkf * 2) ^ ((c & 7) << 4);
                    const bf16x8 bh = *(const bf16x8*)((const char*)sH + off);
                    const bf16x8 bl = *(const bf16x8*)((const char*)sL + off);
                    acc[t] = __builtin_amdgcn_mfma_f32_16x16x32_bf16(ah, bh, acc[t], 0, 0, 0);
                    acc[t] = __builtin_amdgcn_mfma_f32_16x16x32_bf16(al, bh, acc[t], 0, 0, 0);
                    acc[t] = __builtin_amdgcn_mfma_f32_16x16x32_bf16(ah, bl, acc[t], 0, 0, 0);
                }
            }
        }
    }

    if (!valid) return;

    // epilogue: D lane map (m89-verified): col = t*16 + (lane&15), row = m0 + 4*g + r
    float ps[4] = {0.f, 0.f, 0.f, 0.f}, pd[4] = {0.f, 0.f, 0.f, 0.f};
    #pragma unroll
    for (int t = 0; t < 8; ++t) {
        #pragma unroll
        for (int r = 0; r < 4; ++r) {
            const float h = acc[t][r];
            Hb[(size_t)(m0 + 4 * g + r) * FDIM + t * 16 + r16] = f2bf(h);
            ps[r] = fmaf(h, as_r[t], ps[r]);
            pd[r] = fmaf(h, ad_r[t], pd[r]);
        }
    }
    #pragma unroll
    for (int o = 1; o <= 8; o <<= 1) {
        #pragma unroll
        for (int r = 0; r < 4; ++r) {
            ps[r] += __shfl_xor(ps[r], o);
            pd[r] += __shfl_xor(pd[r], o);
        }
    }
    if (r16 == 0) {
        #pragma unroll
        for (int r = 0; r < 4; ++r) {
            asrcN[m0 + 4 * g + r] = ps[r];
            adstN[m0 + 4 * g + r] = pd[r];
        }
    }
}

// ---------------- CSR build ----------------
__global__ void count_edges(const int* __restrict__ ei, int* __restrict__ cnt) {
    int i = blockIdx.x * 256 + threadIdx.x;
    if (i < EN_TOTAL) {
        int d = (i < N_EDGES) ? ei[N_EDGES + i] : (i - N_EDGES);
        atomicAdd(&cnt[d], 1);
    }
}

__global__ __launch_bounds__(256) void scan_block(const int* __restrict__ cnt,
                                                  int* __restrict__ off,
                                                  int* __restrict__ blockSums) {
    __shared__ int s[256];
    const int i = blockIdx.x * 256 + threadIdx.x;
    s[threadIdx.x] = (i < N_NODES) ? cnt[i] : 0;
    __syncthreads();
    #pragma unroll
    for (int d = 1; d < 256; d <<= 1) {
        int t = (threadIdx.x >= d) ? s[threadIdx.x - d] : 0;
        __syncthreads();
        s[threadIdx.x] += t;
        __syncthreads();
    }
    if (i < N_NODES) off[i + 1] = s[threadIdx.x];
    if (threadIdx.x == 255) blockSums[blockIdx.x] = s[255];
}

__global__ __launch_bounds__(256) void scan_sums(int* __restrict__ blockSums) {
    __shared__ int s[256];
    s[threadIdx.x] = (threadIdx.x < SCAN_NB) ? blockSums[threadIdx.x] : 0;
    __syncthreads();
    #pragma unroll
    for (int d = 1; d < 256; d <<= 1) {
        int t = (threadIdx.x >= d) ? s[threadIdx.x - d] : 0;
        __syncthreads();
        s[threadIdx.x] += t;
        __syncthreads();
    }
    if (threadIdx.x < SCAN_NB)
        blockSums[threadIdx.x] = (threadIdx.x == 0) ? 0 : s[threadIdx.x - 1];
}

__global__ __launch_bounds__(256) void add_base(int* __restrict__ off,
                                                const int* __restrict__ blockSums) {
    const int i = blockIdx.x * 256 + threadIdx.x;
    if (i < N_NODES) off[i + 1] += blockSums[blockIdx.x];
    if (i == 0) off[0] = 0;
}

__global__ void scatter_edges(const int* __restrict__ ei, const int* __restrict__ off,
                              int* __restrict__ cur, int* __restrict__ srcs) {
    int i = blockIdx.x * 256 + threadIdx.x;
    if (i < EN_TOTAL) {
        int s, d;
        if (i < N_EDGES) { s = ei[i]; d = ei[N_EDGES + i]; }
        else             { s = d = i - N_EDGES; }
        int p = off[d] + atomicAdd(&cur[d], 1);
        srcs[p] = s;
    }
}

// ---------------- segment softmax + weighted aggregation (bf16 H gather) -------
// One wave per dst node; 8 edge-groups x 8 feature-lanes (16 bf16 feats = 32B).
// mode 0: relu + write bf16 hi/lo planes (next layer's gemm input)
// mode 1: no relu + write fp32 (pool input)
__global__ __launch_bounds__(256) void gat_aggregate(
    const unsigned short* __restrict__ Hb, const int* __restrict__ off,
    const int* __restrict__ srcs,
    const float* __restrict__ asrcN, const float* __restrict__ adstN,
    const float* __restrict__ bias,
    unsigned short* __restrict__ PHI, unsigned short* __restrict__ PLO,
    float* __restrict__ OUTF, int mode)
{
    const int wave = threadIdx.x >> 6, lane = threadIdx.x & 63;
    const int grp = lane >> 3, fl = lane & 7;

    for (int n = blockIdx.x * 4 + wave; n < N_NODES; n += gridDim.x * 4) {
        const int s0 = off[n], s1 = off[n + 1];
        const int deg = s1 - s0;
        const float ad = adstN[n];

        float e_reg = -1e30f;
        float m = -1e30f;
        for (int j = s0 + lane; j < s1; j += 64) {
            float e = lrelu(asrcN[srcs[j]] + ad);
            if (j - s0 < 64) e_reg = e;
            m = fmaxf(m, e);
        }
        #pragma unroll
        for (int o = 32; o; o >>= 1) m = fmaxf(m, __shfl_xor(m, o));

        float4 a0 = {0,0,0,0}, a1 = {0,0,0,0}, a2 = {0,0,0,0}, a3 = {0,0,0,0};
        float dn = 0.f;
        const unsigned short* Hf = Hb + (size_t)fl * 16;
        for (int j = s0 + grp; j < s1; j += 8) {
            const int s = srcs[j];
            const float ex = (deg <= 64)
                ? __expf(__shfl(e_reg, j - s0) - m)
                : __expf(lrelu(asrcN[s] + ad) - m);
            dn += ex;
            const uint4* hp = (const uint4*)(Hf + (size_t)s * FDIM);
            const uint4 u0 = hp[0], u1 = hp[1];
            a0.x += ex * __uint_as_float(u0.x << 16);
            a0.y += ex * __uint_as_float(u0.x & 0xffff0000u);
            a0.z += ex * __uint_as_float(u0.y << 16);
            a0.w += ex * __uint_as_float(u0.y & 0xffff0000u);
            a1.x += ex * __uint_as_float(u0.z << 16);
            a1.y += ex * __uint_as_float(u0.z & 0xffff0000u);
            a1.z += ex * __uint_as_float(u0.w << 16);
            a1.w += ex * __uint_as_float(u0.w & 0xffff0000u);
            a2.x += ex * __uint_as_float(u1.x << 16);
            a2.y += ex * __uint_as_float(u1.x & 0xffff0000u);
            a2.z += ex * __uint_as_float(u1.y << 16);
            a2.w += ex * __uint_as_float(u1.y & 0xffff0000u);
            a3.x += ex * __uint_as_float(u1.z << 16);
            a3.y += ex * __uint_as_float(u1.z & 0xffff0000u);
            a3.z += ex * __uint_as_float(u1.w << 16);
            a3.w += ex * __uint_as_float(u1.w & 0xffff0000u);
        }

        #pragma unroll
        for (int o = 8; o <= 32; o <<= 1) {
            dn  += __shfl_xor(dn, o);
            a0.x += __shfl_xor(a0.x, o); a0.y += __shfl_xor(a0.y, o);
            a0.z += __shfl_xor(a0.z, o); a0.w += __shfl_xor(a0.w, o);
            a1.x += __shfl_xor(a1.x, o); a1.y += __shfl_xor(a1.y, o);
            a1.z += __shfl_xor(a1.z, o); a1.w += __shfl_xor(a1.w, o);
            a2.x += __shfl_xor(a2.x, o); a2.y += __shfl_xor(a2.y, o);
            a2.z += __shfl_xor(a2.z, o); a2.w += __shfl_xor(a2.w, o);
            a3.x += __shfl_xor(a3.x, o); a3.y += __shfl_xor(a3.y, o);
            a3.z += __shfl_xor(a3.z, o); a3.w += __shfl_xor(a3.w, o);
        }

        if (grp == 0) {
            const float rd = 1.f / dn;
            const float4* bp = (const float4*)(bias + fl * 16);
            float4 ov[4] = {a0, a1, a2, a3};
            #pragma unroll
            for (int q = 0; q < 4; ++q) {
                const float4 b4 = bp[q];
                float4 o4;
                o4.x = ov[q].x * rd + b4.x; o4.y = ov[q].y * rd + b4.y;
                o4.z = ov[q].z * rd + b4.z; o4.w = ov[q].w * rd + b4.w;
                if (mode == 0) {
                    o4.x = fmaxf(o4.x, 0.f); o4.y = fmaxf(o4.y, 0.f);
                    o4.z = fmaxf(o4.z, 0.f); o4.w = fmaxf(o4.w, 0.f);
                    ushort4 h4, l4;
                    h4.x = f2bf(o4.x); l4.x = f2bf(o4.x - bf2f(h4.x));
                    h4.y = f2bf(o4.y); l4.y = f2bf(o4.y - bf2f(h4.y));
                    h4.z = f2bf(o4.z); l4.z = f2bf(o4.z - bf2f(h4.z));
                    h4.w = f2bf(o4.w); l4.w = f2bf(o4.w - bf2f(h4.w));
                    const size_t base = (size_t)n * FDIM + fl * 16 + q * 4;
                    *(ushort4*)(PHI + base) = h4;
                    *(ushort4*)(PLO + base) = l4;
                } else {
                    *(float4*)(OUTF + (size_t)n * FDIM + fl * 16 + q * 4) = o4;
                }
            }
        }
    }
}

// ---------------- global mean pool (batch sorted) + final linear ----------------
__global__ __launch_bounds__(128) void pool_linear(
    const float* __restrict__ H, const int* __restrict__ batch,
    const float* __restrict__ Wlin, const float* __restrict__ blin,
    float* __restrict__ out)
{
    const int g = blockIdx.x, f = threadIdx.x;
    int a = 0, b = N_NODES;
    while (a < b) { int mid = (a + b) >> 1; if (batch[mid] < g) a = mid + 1; else b = mid; }
    const int lo = a;
    b = N_NODES;
    while (a < b) { int mid = (a + b) >> 1; if (batch[mid] <= g) a = mid + 1; else b = mid; }
    const int hi = a;

    float acc = 0.f;
    for (int n = lo; n < hi; ++n) acc += H[(size_t)n * FDIM + f];
    const float pooled = acc / fmaxf((float)(hi - lo), 1.0f);

    __shared__ float red0[128], red1[128];
    red0[f] = pooled * Wlin[f * 2 + 0];
    red1[f] = pooled * Wlin[f * 2 + 1];
    __syncthreads();
    for (int st = 64; st; st >>= 1) {
        if (f < st) { red0[f] += red0[f + st]; red1[f] += red1[f + st]; }
        __syncthreads();
    }
    if (f == 0) {
        out[g * 2 + 0] = red0[0] + blin[0];
        out[g * 2 + 1] = red1[0] + blin[1];
    }
}

extern "C" void kernel_launch(void* const* d_in, const int* in_sizes, int n_in,
                              void* d_out, int out_size, void* d_ws, size_t ws_size,
                              hipStream_t stream)
{
    const float* x     = (const float*)d_in[0];
    const int*   ei    = (const int*)d_in[1];
    const int*   batch = (const int*)d_in[2];
    const float* W[3]    = {(const float*)d_in[3],  (const float*)d_in[7],  (const float*)d_in[11]};
    const float* avs[3]  = {(const float*)d_in[4],  (const float*)d_in[8],  (const float*)d_in[12]};
    const float* avd[3]  = {(const float*)d_in[5],  (const float*)d_in[9],  (const float*)d_in[13]};
    const float* bias[3] = {(const float*)d_in[6],  (const float*)d_in[10], (const float*)d_in[14]};
    const float* Wlin = (const float*)d_in[15];
    const float* blin = (const float*)d_in[16];
    float* out = (float*)d_out;

    // workspace: planes (25.6MB, overlaid by final fp32 out), Hb, attn, CSR
    char* w = (char*)d_ws;
    unsigned short* Ahi = (unsigned short*)w; w += (size_t)N_NODES * FDIM * 2;  // 12.8 MB
    unsigned short* Alo = (unsigned short*)w; w += (size_t)N_NODES * FDIM * 2;  // 12.8 MB
    float* hOf = (float*)Ahi;                                                   // overlay (L3 out)
    unsigned short* Hb = (unsigned short*)w; w += (size_t)N_NODES * FDIM * 2;   // 12.8 MB
    float* attn  = (float*)w; w += 2 * 200192;
    int*   off   = (int*)w;   w += 200192;
    int*   cnt   = (int*)w;   w += 200192;
    int*   bsum  = (int*)w;   w += 4096;
    int*   srcs  = (int*)w;   w += (size_t)EN_TOTAL * 4;
    float* asrcN = attn;
    float* adstN = attn + N_NODES;

    // ---- X -> bf16 hi/lo planes ----
    prep_planes<<<1024, 256, 0, stream>>>(x, Ahi, Alo);

    // ---- CSR by destination (topology shared across layers) ----
    hipMemsetAsync(cnt, 0, N_NODES * sizeof(int), stream);
    count_edges<<<(EN_TOTAL + 255) / 256, 256, 0, stream>>>(ei, cnt);
    scan_block<<<SCAN_NB, 256, 0, stream>>>(cnt, off, bsum);
    scan_sums<<<1, 256, 0, stream>>>(bsum);
    add_base<<<SCAN_NB, 256, 0, stream>>>(off, bsum);
    hipMemsetAsync(cnt, 0, N_NODES * sizeof(int), stream);
    scatter_edges<<<(EN_TOTAL + 255) / 256, 256, 0, stream>>>(ei, off, cnt, srcs);

    // ---- 3 GAT layers ----
    const int gemmBlocks = (N_NODES + 63) / 64;   // 782
    for (int l = 0; l < 3; ++l) {
        gemm_mfma<<<gemmBlocks, 256, 0, stream>>>(Ahi, Alo, W[l], avs[l], avd[l],
                                                  Hb, asrcN, adstN);
        gat_aggregate<<<2048, 256, 0, stream>>>(Hb, off, srcs, asrcN, adstN, bias[l],
                                                Ahi, Alo, hOf, (l < 2) ? 0 : 1);
    }

    // ---- mean pool + linear ----
    pool_linear<<<N_GRAPHS, 128, 0, stream>>>(hOf, batch, Wlin, blin, out);
}